// Round 3
// baseline (138.757 us; speedup 1.0000x reference)
//
#include <hip/hip_runtime.h>

#define NQ   12
#define DIM  4096      // 2^NQ
#define NL   2
#define BATCH 4096

typedef float v2f __attribute__((ext_vector_type(2)));

// ---------------------------------------------------------------------------
// One kernel, one block per sample. 256 threads x 16 complex elems (v2f) in
// registers; 12 butterflies in 3 register stages, 2 LDS transposes, 2 barriers.
// Complex math in swap-form so it compiles to v_pk_fma_f32 with op_sel
// (no per-butterfly broadcast movs):  (r+ii)(a+bi) = {r,r}*{a,b} + {-i,i}*{b,a}
// Gates are built redundantly by every wave (lanes 0-11) into LDS; same-wave
// LDS ordering makes the values visible without a barrier.
// Skew off = idx + (idx>>4) keeps all transpose patterns at the LDS BW floor.
// ---------------------------------------------------------------------------

struct PGate { v2f a00, b00, a01, b01, a10, b10, a11, b11; };

// a = {r, r}, b = {-i, i} per matrix entry
__device__ __forceinline__ PGate make_pg(const float* __restrict__ g) {
    PGate p;
    float r00 = g[0], i00 = g[1], r01 = g[2], i01 = g[3];
    float r10 = g[4], i10 = g[5], r11 = g[6], i11 = g[7];
    p.a00 = (v2f){ r00, r00 };  p.b00 = (v2f){ -i00, i00 };
    p.a01 = (v2f){ r01, r01 };  p.b01 = (v2f){ -i01, i01 };
    p.a10 = (v2f){ r10, r10 };  p.b10 = (v2f){ -i10, i10 };
    p.a11 = (v2f){ r11, r11 };  p.b11 = (v2f){ -i11, i11 };
    return p;
}

__device__ __forceinline__ v2f cswap(v2f a) { return (v2f){ a.y, a.x }; }

// y0 = g00*x0 + g01*x1 ; y1 = g10*x0 + g11*x1  (complex, packed re/im)
__device__ __forceinline__ void papply(v2f v[16], int r0, int r1, const PGate& g) {
    v2f x0 = v[r0], x1 = v[r1];
    v2f x0s = cswap(x0), x1s = cswap(x1);
    v[r0] = g.a00 * x0 + g.b00 * x0s + g.a01 * x1 + g.b01 * x1s;
    v[r1] = g.a10 * x0 + g.b10 * x0s + g.a11 * x1 + g.b11 * x1s;
}

// apply gate on register-bit rb (pairs differ in bit rb of the 4-bit reg idx)
__device__ __forceinline__ void papply_rbit(v2f v[16], int rb, const PGate& g) {
    const int m = 1 << rb;
    #pragma unroll
    for (int h = 0; h < 8; ++h) {
        int low = h & (m - 1);
        int r   = ((h & ~(m - 1)) << 1) | low;   // insert 0 at bit rb
        papply(v, r, r | m, g);
    }
}

__device__ __forceinline__ int lds_off(int idx) { return idx + (idx >> 4); }

__global__ __launch_bounds__(256, 4)
void qc_sim(const float* __restrict__ in,
            const float* __restrict__ th,
            const float* __restrict__ ph,
            const float* __restrict__ lm,
            float* __restrict__ out) {
    __shared__ v2f   st[DIM + DIM / 16];   // skewed complex state
    __shared__ float sg[NQ][8];            // fused gates, indexed by bit k
    __shared__ float red[4];

    const int t    = threadIdx.x;
    const int lane = t & 63;
    const int b    = blockIdx.x;

    v2f v[16];
    float ss = 0.f;

    // ---- issue global loads first (coalesced float4) ----
    const float4* __restrict__ x4 =
        reinterpret_cast<const float4*>(in + (size_t)b * DIM);
    #pragma unroll
    for (int j = 0; j < 4; ++j) {
        float4 w = x4[j * 256 + t];
        int r = j * 4;
        v[r]     = (v2f){ w.x, 0.f };
        v[r + 1] = (v2f){ w.y, 0.f };
        v[r + 2] = (v2f){ w.z, 0.f };
        v[r + 3] = (v2f){ w.w, 0.f };
        ss += w.x * w.x + w.y * w.y + w.z * w.z + w.w * w.w;
    }
    #pragma unroll
    for (int off = 32; off > 0; off >>= 1)
        ss += __shfl_down(ss, off, 64);
    if (lane == 0) red[t >> 6] = ss;

    // ---- every wave builds the 12 layer-fused gates (benign identical race;
    //      same-wave LDS ordering => no barrier needed) ----
    if (lane < NQ) {
        int q = lane;
        float g00r = 1.f, g00i = 0.f, g01r = 0.f, g01i = 0.f;
        float g10r = 0.f, g10i = 0.f, g11r = 1.f, g11i = 0.f;
        #pragma unroll
        for (int l = 0; l < NL; ++l) {
            float th2 = 0.5f * th[l * NQ + q];
            float p   = ph[l * NQ + q];
            float la  = lm[l * NQ + q];
            float c = cosf(th2), s = sinf(th2);
            float u00r = c,                u00i = 0.f;
            float u01r = -cosf(la) * s,    u01i = -sinf(la) * s;
            float u10r = cosf(p) * s,      u10i = sinf(p) * s;
            float u11r = cosf(p + la) * c, u11i = sinf(p + la) * c;
            float n00r = u00r*g00r - u00i*g00i + u01r*g10r - u01i*g10i;
            float n00i = u00r*g00i + u00i*g00r + u01r*g10i + u01i*g10r;
            float n01r = u00r*g01r - u00i*g01i + u01r*g11r - u01i*g11i;
            float n01i = u00r*g01i + u00i*g01r + u01r*g11i + u01i*g11r;
            float n10r = u10r*g00r - u10i*g00i + u11r*g10r - u11i*g10i;
            float n10i = u10r*g00i + u10i*g00r + u11r*g10i + u11i*g10r;
            float n11r = u10r*g01r - u10i*g01i + u11r*g11r - u11i*g11i;
            float n11i = u10r*g01i + u10i*g01r + u11r*g11i + u11i*g11r;
            g00r = n00r; g00i = n00i; g01r = n01r; g01i = n01i;
            g10r = n10r; g10i = n10i; g11r = n11r; g11i = n11i;
        }
        int k = (NQ - 1) - q;  // qubit 0 is the MSB of the state index
        sg[k][0] = g00r; sg[k][1] = g00i; sg[k][2] = g01r; sg[k][3] = g01i;
        sg[k][4] = g10r; sg[k][5] = g10i; sg[k][6] = g11r; sg[k][7] = g11i;
    }

    // ---- stage 1: regs = idx bits {0,1,10,11}; gates 0,1,10,11 ----
    {
        // first gate: imaginary inputs exactly zero -> broadcast-x form
        float r00 = sg[0][0], i00 = sg[0][1], r01 = sg[0][2], i01 = sg[0][3];
        float r10 = sg[0][4], i10 = sg[0][5], r11 = sg[0][6], i11 = sg[0][7];
        v2f c00 = (v2f){ r00, i00 }, c01 = (v2f){ r01, i01 };
        v2f c10 = (v2f){ r10, i10 }, c11 = (v2f){ r11, i11 };
        #pragma unroll
        for (int r = 0; r < 16; r += 2) {
            v2f x0 = (v2f){ v[r].x,     v[r].x     };
            v2f x1 = (v2f){ v[r + 1].x, v[r + 1].x };
            v[r]     = c00 * x0 + c01 * x1;
            v[r + 1] = c10 * x0 + c11 * x1;
        }
        { PGate g = make_pg(sg[1]);  papply_rbit(v, 1, g); }
        { PGate g = make_pg(sg[10]); papply_rbit(v, 2, g); }
        { PGate g = make_pg(sg[11]); papply_rbit(v, 3, g); }
    }
    #pragma unroll
    for (int r = 0; r < 16; ++r) {
        int idx = ((r >> 2) << 10) + t * 4 + (r & 3);
        st[lds_off(idx)] = v[r];
    }
    __syncthreads();

    // ---- stage 2: regs = idx bits {2,3,4,5}; gates 2..5 (in-place R/W) ----
    #pragma unroll
    for (int r = 0; r < 16; ++r) {
        int idx = ((t >> 2) << 6) + (r << 2) + (t & 3);
        v[r] = st[lds_off(idx)];
    }
    { PGate g = make_pg(sg[2]); papply_rbit(v, 0, g); }
    { PGate g = make_pg(sg[3]); papply_rbit(v, 1, g); }
    { PGate g = make_pg(sg[4]); papply_rbit(v, 2, g); }
    { PGate g = make_pg(sg[5]); papply_rbit(v, 3, g); }
    #pragma unroll
    for (int r = 0; r < 16; ++r) {
        int idx = ((t >> 2) << 6) + (r << 2) + (t & 3);
        st[lds_off(idx)] = v[r];
    }
    __syncthreads();

    // ---- stage 3: regs = idx bits {6,7,8,9}; gates 6..9 ----
    #pragma unroll
    for (int r = 0; r < 16; ++r) {
        int idx = ((t >> 6) << 10) + (r << 6) + (t & 63);
        v[r] = st[lds_off(idx)];
    }
    { PGate g = make_pg(sg[6]); papply_rbit(v, 0, g); }
    { PGate g = make_pg(sg[7]); papply_rbit(v, 1, g); }
    { PGate g = make_pg(sg[8]); papply_rbit(v, 2, g); }
    { PGate g = make_pg(sg[9]); papply_rbit(v, 3, g); }

    // ---- epilogue: prob = |state|^2 / ||x||^2, coalesced stores ----
    float tot = red[0] + red[1] + red[2] + red[3];
    float inv = 1.0f / tot;
    float* __restrict__ o = out + (size_t)b * DIM;
    #pragma unroll
    for (int r = 0; r < 16; ++r) {
        int idx = ((t >> 6) << 10) + (r << 6) + (t & 63);
        v2f p2 = v[r] * v[r];
        o[idx] = (p2.x + p2.y) * inv;
    }
}

extern "C" void kernel_launch(void* const* d_in, const int* in_sizes, int n_in,
                              void* d_out, int out_size, void* d_ws, size_t ws_size,
                              hipStream_t stream) {
    (void)in_sizes; (void)n_in; (void)out_size; (void)d_ws; (void)ws_size;
    const float* inputs = (const float*)d_in[0];
    const float* thetas = (const float*)d_in[1];
    const float* phis   = (const float*)d_in[2];
    const float* lams   = (const float*)d_in[3];
    float* out = (float*)d_out;

    hipLaunchKernelGGL(qc_sim, dim3(BATCH), dim3(256), 0, stream,
                       inputs, thetas, phis, lams, out);
}

// Round 4
// 133.843 us; speedup vs baseline: 1.0367x; 1.0367x over previous
//
#include <hip/hip_runtime.h>

#define NQ   12
#define DIM  4096      // 2^NQ
#define NL   2
#define BATCH 4096

typedef float v2f __attribute__((ext_vector_type(2)));

// ---------------------------------------------------------------------------
// One kernel, TWO samples per block (A,B). 256 threads x 16 complex elems
// (v2f) per sample in registers; 12 butterflies in 3 register stages.
// One shared 34KB transpose buffer, used alternately by A and B; the barrier
// schedule interleaves samples so every barrier/LDS-latency window is filled
// with the other sample's gate math (ILP covers what TLP at 16 waves/CU
// couldn't: rounds 0-2 were pinned at ~55us with 20-25us of unhidden stall).
// Math is round-1 pk-broadcast form (measured-lowest VALU issue time).
// Skew off = idx + (idx>>4) keeps all transpose patterns at the LDS BW floor.
// ---------------------------------------------------------------------------

struct PGate { v2f a00, b00, a01, b01, a10, b10, a11, b11; };

// a = {r, i}, b = {-i, r}:  y = a*Re(x) + b*Im(x)
__device__ __forceinline__ PGate make_pg(const float* __restrict__ g) {
    PGate p;
    float r00 = g[0], i00 = g[1], r01 = g[2], i01 = g[3];
    float r10 = g[4], i10 = g[5], r11 = g[6], i11 = g[7];
    p.a00 = (v2f){ r00, i00 };  p.b00 = (v2f){ -i00, r00 };
    p.a01 = (v2f){ r01, i01 };  p.b01 = (v2f){ -i01, r01 };
    p.a10 = (v2f){ r10, i10 };  p.b10 = (v2f){ -i10, r10 };
    p.a11 = (v2f){ r11, i11 };  p.b11 = (v2f){ -i11, r11 };
    return p;
}

__device__ __forceinline__ v2f blo(v2f x) { return __builtin_shufflevector(x, x, 0, 0); }
__device__ __forceinline__ v2f bhi(v2f x) { return __builtin_shufflevector(x, x, 1, 1); }

__device__ __forceinline__ void papply(v2f v[16], int r0, int r1, const PGate& g) {
    v2f x0 = v[r0], x1 = v[r1];
    v2f x0r = blo(x0), x0i = bhi(x0), x1r = blo(x1), x1i = bhi(x1);
    v[r0] = g.a00 * x0r + g.b00 * x0i + g.a01 * x1r + g.b01 * x1i;
    v[r1] = g.a10 * x0r + g.b10 * x0i + g.a11 * x1r + g.b11 * x1i;
}

// apply gate on register-bit rb (pairs differ in bit rb of the 4-bit reg idx)
__device__ __forceinline__ void papply_rbit(v2f v[16], int rb, const PGate& g) {
    const int m = 1 << rb;
    #pragma unroll
    for (int h = 0; h < 8; ++h) {
        int low = h & (m - 1);
        int r   = ((h & ~(m - 1)) << 1) | low;   // insert 0 at bit rb
        papply(v, r, r | m, g);
    }
}

__device__ __forceinline__ int lds_off(int idx) { return idx + (idx >> 4); }

// index maps: stage-1 write, stage-2 (read & write-back), stage-3 read
__device__ __forceinline__ int idxW1(int r, int t) { return ((r >> 2) << 10) + (t << 2) + (r & 3); }
__device__ __forceinline__ int idxS2(int r, int t) { return ((t >> 2) << 6) + (r << 2) + (t & 3); }
__device__ __forceinline__ int idxS3(int r, int t) { return ((t >> 6) << 10) + (r << 6) + (t & 63); }

__device__ __forceinline__ void math_s2(v2f v[16], float sg[NQ][8]) {
    { PGate g = make_pg(sg[2]); papply_rbit(v, 0, g); }
    { PGate g = make_pg(sg[3]); papply_rbit(v, 1, g); }
    { PGate g = make_pg(sg[4]); papply_rbit(v, 2, g); }
    { PGate g = make_pg(sg[5]); papply_rbit(v, 3, g); }
}
__device__ __forceinline__ void math_s3(v2f v[16], float sg[NQ][8]) {
    { PGate g = make_pg(sg[6]); papply_rbit(v, 0, g); }
    { PGate g = make_pg(sg[7]); papply_rbit(v, 1, g); }
    { PGate g = make_pg(sg[8]); papply_rbit(v, 2, g); }
    { PGate g = make_pg(sg[9]); papply_rbit(v, 3, g); }
}

__global__ __launch_bounds__(256, 4)
void qc_sim(const float* __restrict__ in,
            const float* __restrict__ th,
            const float* __restrict__ ph,
            const float* __restrict__ lm,
            float* __restrict__ out) {
    __shared__ v2f   st[DIM + DIM / 16];   // skewed transpose buffer (shared A/B)
    __shared__ float sg[NQ][8];            // fused gates, indexed by bit k
    __shared__ float red[8];               // per-wave sumsq: [0..3]=A, [4..7]=B

    const int t    = threadIdx.x;
    const int lane = t & 63;
    const int b    = blockIdx.x;

    const size_t baseA = (size_t)(2 * b) * DIM;
    const size_t baseB = baseA + DIM;

    // ---- issue ALL global loads first (8 x float4, max MLP) ----
    const float4* __restrict__ xA = reinterpret_cast<const float4*>(in + baseA);
    const float4* __restrict__ xB = reinterpret_cast<const float4*>(in + baseB);
    float4 lA[4], lB[4];
    #pragma unroll
    for (int j = 0; j < 4; ++j) lA[j] = xA[j * 256 + t];
    #pragma unroll
    for (int j = 0; j < 4; ++j) lB[j] = xB[j * 256 + t];

    // ---- every wave builds the 12 layer-fused gates (benign identical race;
    //      same-wave LDS ordering => no barrier before stage-1 use) ----
    if (lane < NQ) {
        int q = lane;
        float g00r = 1.f, g00i = 0.f, g01r = 0.f, g01i = 0.f;
        float g10r = 0.f, g10i = 0.f, g11r = 1.f, g11i = 0.f;
        #pragma unroll
        for (int l = 0; l < NL; ++l) {
            float th2 = 0.5f * th[l * NQ + q];
            float p   = ph[l * NQ + q];
            float la  = lm[l * NQ + q];
            float s, c, sl, cl, sp, cp, spl, cpl;
            __sincosf(th2, &s, &c);
            __sincosf(la, &sl, &cl);
            __sincosf(p, &sp, &cp);
            __sincosf(p + la, &spl, &cpl);
            float u00r = c,        u00i = 0.f;
            float u01r = -cl * s,  u01i = -sl * s;
            float u10r = cp * s,   u10i = sp * s;
            float u11r = cpl * c,  u11i = spl * c;
            float n00r = u00r*g00r - u00i*g00i + u01r*g10r - u01i*g10i;
            float n00i = u00r*g00i + u00i*g00r + u01r*g10i + u01i*g10r;
            float n01r = u00r*g01r - u00i*g01i + u01r*g11r - u01i*g11i;
            float n01i = u00r*g01i + u00i*g01r + u01r*g11i + u01i*g11r;
            float n10r = u10r*g00r - u10i*g00i + u11r*g10r - u11i*g10i;
            float n10i = u10r*g00i + u10i*g00r + u11r*g10i + u11i*g10r;
            float n11r = u10r*g01r - u10i*g01i + u11r*g11r - u11i*g11i;
            float n11i = u10r*g01i + u10i*g01r + u11r*g11i + u11i*g11r;
            g00r = n00r; g00i = n00i; g01r = n01r; g01i = n01i;
            g10r = n10r; g10i = n10i; g11r = n11r; g11i = n11i;
        }
        int k = (NQ - 1) - q;  // qubit 0 is the MSB of the state index
        sg[k][0] = g00r; sg[k][1] = g00i; sg[k][2] = g01r; sg[k][3] = g01i;
        sg[k][4] = g10r; sg[k][5] = g10i; sg[k][6] = g11r; sg[k][7] = g11i;
    }

    // ---- sum of squares (both samples), per-wave reduce ----
    float ssA = 0.f, ssB = 0.f;
    #pragma unroll
    for (int j = 0; j < 4; ++j) {
        ssA += lA[j].x*lA[j].x + lA[j].y*lA[j].y + lA[j].z*lA[j].z + lA[j].w*lA[j].w;
        ssB += lB[j].x*lB[j].x + lB[j].y*lB[j].y + lB[j].z*lB[j].z + lB[j].w*lB[j].w;
    }
    #pragma unroll
    for (int off = 32; off > 0; off >>= 1) {
        ssA += __shfl_down(ssA, off, 64);
        ssB += __shfl_down(ssB, off, 64);
    }
    if (lane == 0) { red[t >> 6] = ssA; red[4 + (t >> 6)] = ssB; }

    v2f vA[16], vB[16];

    // ---- stage 1 (gates 0,1,10,11), first gate fed from pure-real input ----
    {
        v2f c00 = (v2f){ sg[0][0], sg[0][1] }, c01 = (v2f){ sg[0][2], sg[0][3] };
        v2f c10 = (v2f){ sg[0][4], sg[0][5] }, c11 = (v2f){ sg[0][6], sg[0][7] };
        #pragma unroll
        for (int j = 0; j < 4; ++j) {
            v2f x0, x1;
            x0 = (v2f){ lA[j].x, lA[j].x }; x1 = (v2f){ lA[j].y, lA[j].y };
            vA[4*j]   = c00 * x0 + c01 * x1;  vA[4*j+1] = c10 * x0 + c11 * x1;
            x0 = (v2f){ lA[j].z, lA[j].z }; x1 = (v2f){ lA[j].w, lA[j].w };
            vA[4*j+2] = c00 * x0 + c01 * x1;  vA[4*j+3] = c10 * x0 + c11 * x1;
            x0 = (v2f){ lB[j].x, lB[j].x }; x1 = (v2f){ lB[j].y, lB[j].y };
            vB[4*j]   = c00 * x0 + c01 * x1;  vB[4*j+1] = c10 * x0 + c11 * x1;
            x0 = (v2f){ lB[j].z, lB[j].z }; x1 = (v2f){ lB[j].w, lB[j].w };
            vB[4*j+2] = c00 * x0 + c01 * x1;  vB[4*j+3] = c10 * x0 + c11 * x1;
        }
        { PGate g = make_pg(sg[1]);  papply_rbit(vA, 1, g); papply_rbit(vB, 1, g); }
        { PGate g = make_pg(sg[10]); papply_rbit(vA, 2, g); papply_rbit(vB, 2, g); }
        { PGate g = make_pg(sg[11]); papply_rbit(vA, 3, g); papply_rbit(vB, 3, g); }
    }

    // ---- interleaved transpose pipeline: every barrier window has math ----
    #pragma unroll
    for (int r = 0; r < 16; ++r) st[lds_off(idxW1(r, t))] = vA[r];      // wrA1
    __syncthreads();                                                     // 1
    #pragma unroll
    for (int r = 0; r < 16; ++r) vA[r] = st[lds_off(idxS2(r, t))];      // rdA1
    __syncthreads();                                                     // 2
    #pragma unroll
    for (int r = 0; r < 16; ++r) st[lds_off(idxW1(r, t))] = vB[r];      // wrB1
    __syncthreads();                                                     // 3
    #pragma unroll
    for (int r = 0; r < 16; ++r) vB[r] = st[lds_off(idxS2(r, t))];      // rdB1
    math_s2(vA, sg);                                  // overlaps rdB1 latency
    __syncthreads();                                                     // 4
    #pragma unroll
    for (int r = 0; r < 16; ++r) st[lds_off(idxS2(r, t))] = vA[r];      // wrA2
    __syncthreads();                                                     // 5
    #pragma unroll
    for (int r = 0; r < 16; ++r) vA[r] = st[lds_off(idxS3(r, t))];      // rdA2
    math_s2(vB, sg);                                  // overlaps rdA2 latency
    __syncthreads();                                                     // 6
    #pragma unroll
    for (int r = 0; r < 16; ++r) st[lds_off(idxS2(r, t))] = vB[r];      // wrB2
    __syncthreads();                                                     // 7
    #pragma unroll
    for (int r = 0; r < 16; ++r) vB[r] = st[lds_off(idxS3(r, t))];      // rdB2
    math_s3(vA, sg);                                  // overlaps rdB2 latency

    // ---- epilogue A, then finish B ----
    {
        float inv = 1.0f / (red[0] + red[1] + red[2] + red[3]);
        float* __restrict__ o = out + baseA;
        #pragma unroll
        for (int r = 0; r < 16; ++r) {
            v2f p2 = vA[r] * vA[r];
            o[idxS3(r, t)] = (p2.x + p2.y) * inv;
        }
    }
    math_s3(vB, sg);
    {
        float inv = 1.0f / (red[4] + red[5] + red[6] + red[7]);
        float* __restrict__ o = out + baseB;
        #pragma unroll
        for (int r = 0; r < 16; ++r) {
            v2f p2 = vB[r] * vB[r];
            o[idxS3(r, t)] = (p2.x + p2.y) * inv;
        }
    }
}

extern "C" void kernel_launch(void* const* d_in, const int* in_sizes, int n_in,
                              void* d_out, int out_size, void* d_ws, size_t ws_size,
                              hipStream_t stream) {
    (void)in_sizes; (void)n_in; (void)out_size; (void)d_ws; (void)ws_size;
    const float* inputs = (const float*)d_in[0];
    const float* thetas = (const float*)d_in[1];
    const float* phis   = (const float*)d_in[2];
    const float* lams   = (const float*)d_in[3];
    float* out = (float*)d_out;

    hipLaunchKernelGGL(qc_sim, dim3(BATCH / 2), dim3(256), 0, stream,
                       inputs, thetas, phis, lams, out);
}

// Round 5
// 133.570 us; speedup vs baseline: 1.0388x; 1.0020x over previous
//
#include <hip/hip_runtime.h>

#define NQ   12
#define DIM  4096      // 2^NQ
#define NL   2
#define BATCH 4096

typedef float v2f __attribute__((ext_vector_type(2)));

// ---------------------------------------------------------------------------
// One kernel, one block per sample. 256 threads x 16 complex elems (v2f) in
// registers; 12 butterflies in 3 register stages, 2 LDS transposes, but only
// ONE block barrier:
//   - transpose 1 is WAVE-LOCAL: wave bits (t6,t7) are pinned to idx bits
//     {8,9} in both the stage-1 and stage-2 layouts, so data only moves
//     within a wave; same-wave DS in-order visibility (validated by the
//     barrier-less gate build since round 2) replaces __syncthreads.
//   - transpose 2's writes hit the same per-thread slots transpose 1 read
//     (thread-private WAR, data-dependent through the gate math) -> no
//     barrier; one barrier before its cross-wave reads.
// Layouts (elem bits <- source):
//   map1: {0,1}<-r0r1(e), {2..7}<-t0..t5, {8,9}<-t6t7(wave), {10,11}<-r2r3(j)
//   map2: {0,1}<-t0t1, {2,3}<-r0r1, {4,5}<-r2r3, {6,7}<-t2t3,
//         {8,9}<-t6t7(wave), {10,11}<-t4t5
//   map3: {0..5}<-t0..t5, {6..9}<-r, {10,11}<-t6t7   (coalesced stores)
// Gates per stage: s1: bits 0,1,10,11 ; s2: bits 2..5 ; s3: bits 6..9.
// Skew off = idx + (idx>>4): all three patterns sit at the b64 bank floor.
// Math is round-1/2 pk-broadcast form (measured-lowest VALU issue).
// ---------------------------------------------------------------------------

struct PGate { v2f a00, b00, a01, b01, a10, b10, a11, b11; };

// a = {r, i}, b = {-i, r}:  y = a*Re(x) + b*Im(x)
__device__ __forceinline__ PGate make_pg(const float* __restrict__ g) {
    PGate p;
    float r00 = g[0], i00 = g[1], r01 = g[2], i01 = g[3];
    float r10 = g[4], i10 = g[5], r11 = g[6], i11 = g[7];
    p.a00 = (v2f){ r00, i00 };  p.b00 = (v2f){ -i00, r00 };
    p.a01 = (v2f){ r01, i01 };  p.b01 = (v2f){ -i01, r01 };
    p.a10 = (v2f){ r10, i10 };  p.b10 = (v2f){ -i10, r10 };
    p.a11 = (v2f){ r11, i11 };  p.b11 = (v2f){ -i11, r11 };
    return p;
}

__device__ __forceinline__ v2f blo(v2f x) { return __builtin_shufflevector(x, x, 0, 0); }
__device__ __forceinline__ v2f bhi(v2f x) { return __builtin_shufflevector(x, x, 1, 1); }

__device__ __forceinline__ void papply(v2f v[16], int r0, int r1, const PGate& g) {
    v2f x0 = v[r0], x1 = v[r1];
    v2f x0r = blo(x0), x0i = bhi(x0), x1r = blo(x1), x1i = bhi(x1);
    v[r0] = g.a00 * x0r + g.b00 * x0i + g.a01 * x1r + g.b01 * x1i;
    v[r1] = g.a10 * x0r + g.b10 * x0i + g.a11 * x1r + g.b11 * x1i;
}

// apply gate on register-bit rb (pairs differ in bit rb of the 4-bit reg idx)
__device__ __forceinline__ void papply_rbit(v2f v[16], int rb, const PGate& g) {
    const int m = 1 << rb;
    #pragma unroll
    for (int h = 0; h < 8; ++h) {
        int low = h & (m - 1);
        int r   = ((h & ~(m - 1)) << 1) | low;   // insert 0 at bit rb
        papply(v, r, r | m, g);
    }
}

__device__ __forceinline__ int lds_off(int idx) { return idx + (idx >> 4); }

__device__ __forceinline__ int map1(int r, int t) {
    return ((r >> 2) << 10) | (t << 2) | (r & 3);
}
__device__ __forceinline__ int map2(int r, int t) {
    return (t & 3) | ((r & 3) << 2) | (((r >> 2) & 3) << 4)
         | (((t >> 2) & 3) << 6) | (((t >> 6) & 3) << 8) | (((t >> 4) & 3) << 10);
}
__device__ __forceinline__ int map3(int r, int t) {
    return (t & 63) | (r << 6) | ((t >> 6) << 10);
}

__global__ __launch_bounds__(256, 4)
void qc_sim(const float* __restrict__ in,
            const float* __restrict__ th,
            const float* __restrict__ ph,
            const float* __restrict__ lm,
            float* __restrict__ out) {
    __shared__ v2f   st[DIM + DIM / 16];   // skewed transpose buffer
    __shared__ float sg[NQ][8];            // fused gates, indexed by bit k
    __shared__ float red[4];               // per-wave sumsq

    const int t    = threadIdx.x;
    const int lane = t & 63;
    const int b    = blockIdx.x;

    // ---- issue global loads first (coalesced float4) ----
    const float4* __restrict__ x4 =
        reinterpret_cast<const float4*>(in + (size_t)b * DIM);
    float4 lA[4];
    #pragma unroll
    for (int j = 0; j < 4; ++j) lA[j] = x4[j * 256 + t];

    // ---- every wave builds the 12 layer-fused gates (benign identical race;
    //      same-wave DS in-order visibility => no barrier needed) ----
    if (lane < NQ) {
        int q = lane;
        float g00r = 1.f, g00i = 0.f, g01r = 0.f, g01i = 0.f;
        float g10r = 0.f, g10i = 0.f, g11r = 1.f, g11i = 0.f;
        #pragma unroll
        for (int l = 0; l < NL; ++l) {
            float th2 = 0.5f * th[l * NQ + q];
            float p   = ph[l * NQ + q];
            float la  = lm[l * NQ + q];
            float s, c, sl, cl, sp, cp, spl, cpl;
            __sincosf(th2, &s, &c);
            __sincosf(la, &sl, &cl);
            __sincosf(p, &sp, &cp);
            __sincosf(p + la, &spl, &cpl);
            float u00r = c,        u00i = 0.f;
            float u01r = -cl * s,  u01i = -sl * s;
            float u10r = cp * s,   u10i = sp * s;
            float u11r = cpl * c,  u11i = spl * c;
            float n00r = u00r*g00r - u00i*g00i + u01r*g10r - u01i*g10i;
            float n00i = u00r*g00i + u00i*g00r + u01r*g10i + u01i*g10r;
            float n01r = u00r*g01r - u00i*g01i + u01r*g11r - u01i*g11i;
            float n01i = u00r*g01i + u00i*g01r + u01r*g11i + u01i*g11r;
            float n10r = u10r*g00r - u10i*g00i + u11r*g10r - u11i*g10i;
            float n10i = u10r*g00i + u10i*g00r + u11r*g10i + u11i*g10r;
            float n11r = u10r*g01r - u10i*g01i + u11r*g11r - u11i*g11i;
            float n11i = u10r*g01i + u10i*g01r + u11r*g11i + u11i*g11r;
            g00r = n00r; g00i = n00i; g01r = n01r; g01i = n01i;
            g10r = n10r; g10i = n10i; g11r = n11r; g11i = n11i;
        }
        int k = (NQ - 1) - q;  // qubit 0 is the MSB of the state index
        sg[k][0] = g00r; sg[k][1] = g00i; sg[k][2] = g01r; sg[k][3] = g01i;
        sg[k][4] = g10r; sg[k][5] = g10i; sg[k][6] = g11r; sg[k][7] = g11i;
    }

    // ---- sum of squares, per-wave reduce ----
    float ss = 0.f;
    #pragma unroll
    for (int j = 0; j < 4; ++j)
        ss += lA[j].x*lA[j].x + lA[j].y*lA[j].y + lA[j].z*lA[j].z + lA[j].w*lA[j].w;
    #pragma unroll
    for (int off = 32; off > 0; off >>= 1)
        ss += __shfl_down(ss, off, 64);
    if (lane == 0) red[t >> 6] = ss;

    v2f v[16];

    // ---- stage 1 (gates 0,1,10,11), first gate fed from pure-real input ----
    {
        v2f c00 = (v2f){ sg[0][0], sg[0][1] }, c01 = (v2f){ sg[0][2], sg[0][3] };
        v2f c10 = (v2f){ sg[0][4], sg[0][5] }, c11 = (v2f){ sg[0][6], sg[0][7] };
        #pragma unroll
        for (int j = 0; j < 4; ++j) {
            v2f x0, x1;
            x0 = (v2f){ lA[j].x, lA[j].x }; x1 = (v2f){ lA[j].y, lA[j].y };
            v[4*j]   = c00 * x0 + c01 * x1;  v[4*j+1] = c10 * x0 + c11 * x1;
            x0 = (v2f){ lA[j].z, lA[j].z }; x1 = (v2f){ lA[j].w, lA[j].w };
            v[4*j+2] = c00 * x0 + c01 * x1;  v[4*j+3] = c10 * x0 + c11 * x1;
        }
        { PGate g = make_pg(sg[1]);  papply_rbit(v, 1, g); }
        { PGate g = make_pg(sg[10]); papply_rbit(v, 2, g); }
        { PGate g = make_pg(sg[11]); papply_rbit(v, 3, g); }
    }

    // ---- transpose 1: WAVE-LOCAL (map1 -> map2), no block barrier ----
    #pragma unroll
    for (int r = 0; r < 16; ++r) st[lds_off(map1(r, t))] = v[r];
    #pragma unroll
    for (int r = 0; r < 16; ++r) v[r] = st[lds_off(map2(r, t))];

    // ---- stage 2 (gates on idx bits 2..5) ----
    { PGate g = make_pg(sg[2]); papply_rbit(v, 0, g); }
    { PGate g = make_pg(sg[3]); papply_rbit(v, 1, g); }
    { PGate g = make_pg(sg[4]); papply_rbit(v, 2, g); }
    { PGate g = make_pg(sg[5]); papply_rbit(v, 3, g); }

    // ---- transpose 2: write back to own map2 slots (thread-private WAR),
    //      ONE barrier, cross-wave read at map3 ----
    #pragma unroll
    for (int r = 0; r < 16; ++r) st[lds_off(map2(r, t))] = v[r];
    __syncthreads();
    #pragma unroll
    for (int r = 0; r < 16; ++r) v[r] = st[lds_off(map3(r, t))];

    // ---- stage 3 (gates on idx bits 6..9) ----
    { PGate g = make_pg(sg[6]); papply_rbit(v, 0, g); }
    { PGate g = make_pg(sg[7]); papply_rbit(v, 1, g); }
    { PGate g = make_pg(sg[8]); papply_rbit(v, 2, g); }
    { PGate g = make_pg(sg[9]); papply_rbit(v, 3, g); }

    // ---- epilogue: prob = |state|^2 / ||x||^2, coalesced stores ----
    float inv = 1.0f / (red[0] + red[1] + red[2] + red[3]);
    float* __restrict__ o = out + (size_t)b * DIM;
    #pragma unroll
    for (int r = 0; r < 16; ++r) {
        v2f p2 = v[r] * v[r];
        o[map3(r, t)] = (p2.x + p2.y) * inv;
    }
}

extern "C" void kernel_launch(void* const* d_in, const int* in_sizes, int n_in,
                              void* d_out, int out_size, void* d_ws, size_t ws_size,
                              hipStream_t stream) {
    (void)in_sizes; (void)n_in; (void)out_size; (void)d_ws; (void)ws_size;
    const float* inputs = (const float*)d_in[0];
    const float* thetas = (const float*)d_in[1];
    const float* phis   = (const float*)d_in[2];
    const float* lams   = (const float*)d_in[3];
    float* out = (float*)d_out;

    hipLaunchKernelGGL(qc_sim, dim3(BATCH), dim3(256), 0, stream,
                       inputs, thetas, phis, lams, out);
}

// Round 6
// 129.556 us; speedup vs baseline: 1.0710x; 1.0310x over previous
//
#include <hip/hip_runtime.h>

#define NQ   12
#define DIM  4096      // 2^NQ
#define NL   2
#define BATCH 4096

typedef float v2f __attribute__((ext_vector_type(2)));

// ---------------------------------------------------------------------------
// Two kernels.
// build_gates: 12 threads fuse the NL layers per qubit ((A⊗B..)(C⊗D..) =
//   (AC)⊗(BD)..) and store each gate in pre-negated PGate form (16 floats):
//   a = {r, i}, b = {-i, r} per matrix entry, so qc_sim does ZERO gate prep.
// qc_sim: one block per sample, 256 threads x 16 complex elems (v2f) in
//   registers; 12 butterflies in 3 register stages, 2 LDS transposes, ONE
//   block barrier (transpose 1 is wave-local: wave bits t6,t7 pinned to idx
//   bits {8,9} in both layouts; transpose 2 writes thread-private slots).
//   Gates are read at compile-time-constant uniform global addresses ->
//   scalar loads -> SGPR-resident (v_pk_fma takes one SGPR operand), which
//   removes the 96 broadcast ds_read_b32/wave that round-5 spent on gates
//   (gate DS reads exceeded the transpose DS traffic and serialized with
//   the dependent papply chains).
// Layouts (elem bits <- source):
//   map1: {0,1}<-r0r1(e), {2..7}<-t0..t5, {8,9}<-t6t7(wave), {10,11}<-r2r3(j)
//   map2: {0,1}<-t0t1, {2,3}<-r0r1, {4,5}<-r2r3, {6,7}<-t2t3,
//         {8,9}<-t6t7(wave), {10,11}<-t4t5
//   map3: {0..5}<-t0..t5, {6..9}<-r, {10,11}<-t6t7   (coalesced stores)
// Gates per stage: s1: bits 0,1,10,11 ; s2: bits 2..5 ; s3: bits 6..9.
// Skew off = idx + (idx>>4): all three patterns sit at the b64 bank floor.
// ---------------------------------------------------------------------------

struct PGate { v2f a00, b00, a01, b01, a10, b10, a11, b11; };

__global__ void build_gates(const float* __restrict__ th,
                            const float* __restrict__ ph,
                            const float* __restrict__ lm,
                            float* __restrict__ gates) {
    int q = threadIdx.x;
    if (q >= NQ) return;
    float g00r = 1.f, g00i = 0.f, g01r = 0.f, g01i = 0.f;
    float g10r = 0.f, g10i = 0.f, g11r = 1.f, g11i = 0.f;
    #pragma unroll
    for (int l = 0; l < NL; ++l) {
        float th2 = 0.5f * th[l * NQ + q];
        float p   = ph[l * NQ + q];
        float la  = lm[l * NQ + q];
        float s, c, sl, cl, sp, cp, spl, cpl;
        __sincosf(th2, &s, &c);
        __sincosf(la, &sl, &cl);
        __sincosf(p, &sp, &cp);
        __sincosf(p + la, &spl, &cpl);
        float u00r = c,        u00i = 0.f;
        float u01r = -cl * s,  u01i = -sl * s;
        float u10r = cp * s,   u10i = sp * s;
        float u11r = cpl * c,  u11i = spl * c;
        float n00r = u00r*g00r - u00i*g00i + u01r*g10r - u01i*g10i;
        float n00i = u00r*g00i + u00i*g00r + u01r*g10i + u01i*g10r;
        float n01r = u00r*g01r - u00i*g01i + u01r*g11r - u01i*g11i;
        float n01i = u00r*g01i + u00i*g01r + u01r*g11i + u01i*g11r;
        float n10r = u10r*g00r - u10i*g00i + u11r*g10r - u11i*g10i;
        float n10i = u10r*g00i + u10i*g00r + u11r*g10i + u11i*g10r;
        float n11r = u10r*g01r - u10i*g01i + u11r*g11r - u11i*g11i;
        float n11i = u10r*g01i + u10i*g01r + u11r*g11i + u11i*g11r;
        g00r = n00r; g00i = n00i; g01r = n01r; g01i = n01i;
        g10r = n10r; g10i = n10i; g11r = n11r; g11i = n11i;
    }
    int k = (NQ - 1) - q;  // qubit 0 is the MSB of the state index
    float* o = gates + k * 16;
    o[0]  = g00r;  o[1]  = g00i;  o[2]  = -g00i; o[3]  = g00r;   // a00, b00
    o[4]  = g01r;  o[5]  = g01i;  o[6]  = -g01i; o[7]  = g01r;   // a01, b01
    o[8]  = g10r;  o[9]  = g10i;  o[10] = -g10i; o[11] = g10r;   // a10, b10
    o[12] = g11r;  o[13] = g11i;  o[14] = -g11i; o[15] = g11r;   // a11, b11
}

__device__ __forceinline__ v2f blo(v2f x) { return __builtin_shufflevector(x, x, 0, 0); }
__device__ __forceinline__ v2f bhi(v2f x) { return __builtin_shufflevector(x, x, 1, 1); }

__device__ __forceinline__ void papply(v2f v[16], int r0, int r1, const PGate& g) {
    v2f x0 = v[r0], x1 = v[r1];
    v2f x0r = blo(x0), x0i = bhi(x0), x1r = blo(x1), x1i = bhi(x1);
    v[r0] = g.a00 * x0r + g.b00 * x0i + g.a01 * x1r + g.b01 * x1i;
    v[r1] = g.a10 * x0r + g.b10 * x0i + g.a11 * x1r + g.b11 * x1i;
}

// apply gate on register-bit rb (pairs differ in bit rb of the 4-bit reg idx)
__device__ __forceinline__ void papply_rbit(v2f v[16], int rb, const PGate& g) {
    const int m = 1 << rb;
    #pragma unroll
    for (int h = 0; h < 8; ++h) {
        int low = h & (m - 1);
        int r   = ((h & ~(m - 1)) << 1) | low;   // insert 0 at bit rb
        papply(v, r, r | m, g);
    }
}

__device__ __forceinline__ int lds_off(int idx) { return idx + (idx >> 4); }

__device__ __forceinline__ int map1(int r, int t) {
    return ((r >> 2) << 10) | (t << 2) | (r & 3);
}
__device__ __forceinline__ int map2(int r, int t) {
    return (t & 3) | ((r & 3) << 2) | (((r >> 2) & 3) << 4)
         | (((t >> 2) & 3) << 6) | (((t >> 6) & 3) << 8) | (((t >> 4) & 3) << 10);
}
__device__ __forceinline__ int map3(int r, int t) {
    return (t & 63) | (r << 6) | ((t >> 6) << 10);
}

__global__ __launch_bounds__(256, 4)
void qc_sim(const float* __restrict__ in,
            const PGate* __restrict__ gp,
            float* __restrict__ out) {
    __shared__ v2f   st[DIM + DIM / 16];   // skewed transpose buffer
    __shared__ float red[4];               // per-wave sumsq

    const int t    = threadIdx.x;
    const int lane = t & 63;
    const int b    = blockIdx.x;

    // ---- issue global loads first (coalesced float4) ----
    const float4* __restrict__ x4 =
        reinterpret_cast<const float4*>(in + (size_t)b * DIM);
    float4 lA[4];
    #pragma unroll
    for (int j = 0; j < 4; ++j) lA[j] = x4[j * 256 + t];

    // ---- sum of squares, per-wave reduce ----
    float ss = 0.f;
    #pragma unroll
    for (int j = 0; j < 4; ++j)
        ss += lA[j].x*lA[j].x + lA[j].y*lA[j].y + lA[j].z*lA[j].z + lA[j].w*lA[j].w;
    #pragma unroll
    for (int off = 32; off > 0; off >>= 1)
        ss += __shfl_down(ss, off, 64);
    if (lane == 0) red[t >> 6] = ss;

    v2f v[16];

    // ---- stage 1 (gates 0,1,10,11), first gate fed from pure-real input ----
    {
        PGate g0 = gp[0];
        #pragma unroll
        for (int j = 0; j < 4; ++j) {
            v2f x0, x1;
            x0 = (v2f){ lA[j].x, lA[j].x }; x1 = (v2f){ lA[j].y, lA[j].y };
            v[4*j]   = g0.a00 * x0 + g0.a01 * x1;  v[4*j+1] = g0.a10 * x0 + g0.a11 * x1;
            x0 = (v2f){ lA[j].z, lA[j].z }; x1 = (v2f){ lA[j].w, lA[j].w };
            v[4*j+2] = g0.a00 * x0 + g0.a01 * x1;  v[4*j+3] = g0.a10 * x0 + g0.a11 * x1;
        }
        { PGate g = gp[1];  papply_rbit(v, 1, g); }
        { PGate g = gp[10]; papply_rbit(v, 2, g); }
        { PGate g = gp[11]; papply_rbit(v, 3, g); }
    }

    // ---- transpose 1: WAVE-LOCAL (map1 -> map2), no block barrier ----
    #pragma unroll
    for (int r = 0; r < 16; ++r) st[lds_off(map1(r, t))] = v[r];
    #pragma unroll
    for (int r = 0; r < 16; ++r) v[r] = st[lds_off(map2(r, t))];

    // ---- stage 2 (gates on idx bits 2..5) ----
    { PGate g = gp[2]; papply_rbit(v, 0, g); }
    { PGate g = gp[3]; papply_rbit(v, 1, g); }
    { PGate g = gp[4]; papply_rbit(v, 2, g); }
    { PGate g = gp[5]; papply_rbit(v, 3, g); }

    // ---- transpose 2: write back to own map2 slots (thread-private WAR),
    //      ONE barrier, cross-wave read at map3 ----
    #pragma unroll
    for (int r = 0; r < 16; ++r) st[lds_off(map2(r, t))] = v[r];
    __syncthreads();
    #pragma unroll
    for (int r = 0; r < 16; ++r) v[r] = st[lds_off(map3(r, t))];

    // ---- stage 3 (gates on idx bits 6..9) ----
    { PGate g = gp[6]; papply_rbit(v, 0, g); }
    { PGate g = gp[7]; papply_rbit(v, 1, g); }
    { PGate g = gp[8]; papply_rbit(v, 2, g); }
    { PGate g = gp[9]; papply_rbit(v, 3, g); }

    // ---- epilogue: prob = |state|^2 / ||x||^2, coalesced stores ----
    float inv = 1.0f / (red[0] + red[1] + red[2] + red[3]);
    float* __restrict__ o = out + (size_t)b * DIM;
    #pragma unroll
    for (int r = 0; r < 16; ++r) {
        v2f p2 = v[r] * v[r];
        o[map3(r, t)] = (p2.x + p2.y) * inv;
    }
}

extern "C" void kernel_launch(void* const* d_in, const int* in_sizes, int n_in,
                              void* d_out, int out_size, void* d_ws, size_t ws_size,
                              hipStream_t stream) {
    (void)in_sizes; (void)n_in; (void)out_size; (void)ws_size;
    const float* inputs = (const float*)d_in[0];
    const float* thetas = (const float*)d_in[1];
    const float* phis   = (const float*)d_in[2];
    const float* lams   = (const float*)d_in[3];
    float* gates = (float*)d_ws;              // 192 floats of scratch
    float* out   = (float*)d_out;

    hipLaunchKernelGGL(build_gates, dim3(1), dim3(64), 0, stream,
                       thetas, phis, lams, gates);
    hipLaunchKernelGGL(qc_sim, dim3(BATCH), dim3(256), 0, stream,
                       inputs, (const PGate*)gates, out);
}